// Round 10
// baseline (784.738 us; speedup 1.0000x reference)
//
#include <hip/hip_runtime.h>
#include <math.h>

// ---------------- helpers ----------------
__device__ __forceinline__ unsigned short f2bf(float f){   // RTN bf16
    unsigned u = __float_as_uint(f);
    unsigned r = u + 0x7fffu + ((u >> 16) & 1u);
    return (unsigned short)(r >> 16);
}

// ---------------- CSR build ----------------
__global__ void k_zero_i(int* __restrict__ p, int n)
{
    for (int i = blockIdx.x*blockDim.x + threadIdx.x; i < n; i += gridDim.x*blockDim.x)
        p[i] = 0;
}

__global__ void k_count(const int* __restrict__ ef, const int* __restrict__ er,
                        int* __restrict__ deg, int Ef, int Er)
{
    int Etot = Ef + Er;
    for (int e = blockIdx.x*blockDim.x + threadIdx.x; e < Etot; e += gridDim.x*blockDim.x) {
        int dst = (e < Ef) ? ef[Ef + e] : er[Er + (e - Ef)];
        atomicAdd(&deg[dst], 1);
    }
}

__global__ void k_chunk_sums(const int* __restrict__ deg, int* __restrict__ csum, int n)
{
    __shared__ int s[256];
    int t = threadIdx.x, i = blockIdx.x*256 + t;
    s[t] = (i < n) ? deg[i] : 0;
    __syncthreads();
    for (int off = 128; off > 0; off >>= 1) {
        if (t < off) s[t] += s[t + off];
        __syncthreads();
    }
    if (t == 0) csum[blockIdx.x] = s[0];
}

__global__ void k_scan_chunks(int* __restrict__ csum, int nch)
{
    __shared__ int s[1024];
    int t = threadIdx.x;
    int v = (t < nch) ? csum[t] : 0;
    s[t] = v; __syncthreads();
    for (int off = 1; off < 1024; off <<= 1) {
        int u = (t >= off) ? s[t - off] : 0;
        __syncthreads();
        s[t] += u;
        __syncthreads();
    }
    if (t < nch) csum[t] = s[t] - v;
}

__global__ void k_rowstart(const int* __restrict__ deg, const int* __restrict__ csum,
                           int* __restrict__ row_start, int* __restrict__ cursor, int n)
{
    __shared__ int s[256];
    int t = threadIdx.x, i = blockIdx.x*256 + t;
    int d = (i < n) ? deg[i] : 0;
    s[t] = d; __syncthreads();
    for (int off = 1; off < 256; off <<= 1) {
        int u = (t >= off) ? s[t - off] : 0;
        __syncthreads();
        s[t] += u;
        __syncthreads();
    }
    if (i <= n) {
        int rs = csum[blockIdx.x] + s[t] - d;   // exclusive
        row_start[i] = rs;
        cursor[i] = rs;
    }
}

__global__ void k_fill(const int* __restrict__ ef, const int* __restrict__ er,
                       int* __restrict__ cursor, unsigned* __restrict__ srcs,
                       int Ef, int Er)
{
    int Etot = Ef + Er;
    for (int e = blockIdx.x*blockDim.x + threadIdx.x; e < Etot; e += gridDim.x*blockDim.x) {
        int src, dst; unsigned tbit;
        if (e < Ef) { src = ef[e]; dst = ef[Ef + e]; tbit = 0u; }
        else { int e2 = e - Ef; src = er[e2]; dst = er[Er + e2]; tbit = 0x80000000u; }
        int pos = atomicAdd(&cursor[dst], 1);
        srcs[pos] = (unsigned)src | tbit;
    }
}

// ---------------- composed weights ----------------
// Wc[l] 129 x 640 (row 128 = bias):
//   cols   0-127: q
//   cols 128-639: per edge type tt (256 cols each), interleaved per feature:
//     col 128 + tt*256 + 2f   = krel feature f (p*scale folded)
//     col 128 + tt*256 + 2f+1 = vrel feature f
__global__ void k_compose(const float* __restrict__ kqv_w, const float* __restrict__ kqv_b,
                          const float* __restrict__ krel_w, const float* __restrict__ vrel_w,
                          const float* __restrict__ p_rel, float* __restrict__ Wc)
{
    int idx = blockIdx.x*blockDim.x + threadIdx.x;
    int tot = 2*129*640;
    if (idx >= tot) return;
    int l = idx / (129*640);
    int rem = idx % (129*640);
    int r = rem / 640, c = rem % 640;
    float val;
    if (c < 128) {
        val = (r < 128) ? kqv_w[((size_t)l*128 + r)*384 + 128 + c]
                        : kqv_b[l*384 + 128 + c];
    } else {
        int c2 = c - 128;
        int tt = c2 >> 8;
        int cc = c2 & 255;
        int f = cc >> 1;
        int part = cc & 1;             // 0 = k, 1 = v
        int hh = f >> 4, fd = f & 15;
        const float* rw = (part == 0 ? krel_w : vrel_w)
                          + (((size_t)(l*2 + tt)*8 + hh)*16)*16 + fd;
        int base_col = (part == 0 ? 0 : 256) + hh*16;
        float s = 0.f;
        #pragma unroll
        for (int d = 0; d < 16; ++d) {
            float a = (r < 128) ? kqv_w[((size_t)l*128 + r)*384 + base_col + d]
                                : kqv_b[l*384 + base_col + d];
            s += a * rw[d*16];
        }
        if (part == 0) s *= p_rel[(l*2 + tt)*8 + hh] * 0.25f;
        val = s;
    }
    Wc[idx] = val;
}

// ---------------- tiled GEMM: block owns a 64-row tile, loops ALL col tiles ----------------
// A tile (64x128) staged ONCE in LDS (transposed + XOR swizzle); per col tile a
// 32x64 W tile is staged per BK step. 256 threads, 4x4 register tile.
// mode 0: plain f32 store; mode 1: cols<128 q f32, cols>=128 interleaved kv -> packed bf16;
// mode 2: h = relu(g*C + (1-g)*h)
__global__ __launch_bounds__(256) void k_gemm(
    const float* __restrict__ A, const float* __restrict__ W, int ncols,
    const float* __restrict__ bias, float* __restrict__ out0,
    unsigned* __restrict__ kv, const float* __restrict__ skip, int l,
    int n_nodes, int mode)
{
    __shared__ float As_t[128][64];    // 32 KB: element (k, m) at col m ^ ((k>>2 & 7)<<3)
    __shared__ float Ws[32][64];       // 8 KB
    int n0 = blockIdx.x*64;
    int t = threadIdx.x, tx = t & 15, ty = t >> 4;

    // stage full A tile once
    #pragma unroll
    for (int it = 0; it < 8; ++it) {
        int idx = t + it*256;              // [0, 2048)
        int m = idx >> 5, c4 = idx & 31;   // row m, k-float4 index
        int n = n0 + m;
        float4 a = make_float4(0.f, 0.f, 0.f, 0.f);
        if (n < n_nodes) a = *(const float4*)&A[(size_t)n*128 + c4*4];
        int col = m ^ ((c4 & 7) << 3);
        As_t[c4*4 + 0][col] = a.x;
        As_t[c4*4 + 1][col] = a.y;
        As_t[c4*4 + 2][col] = a.z;
        As_t[c4*4 + 3][col] = a.w;
    }

    float g = (mode == 2) ? 1.f/(1.f + expf(-skip[l])) : 0.f;
    int ncc = ncols >> 6;
    for (int cc = 0; cc < ncc; ++cc) {
        int c0 = cc*64;
        float4 b4 = *(const float4*)&bias[c0 + tx*4];
        float acc[4][4];
        #pragma unroll
        for (int r = 0; r < 4; ++r) {
            acc[r][0] = b4.x; acc[r][1] = b4.y; acc[r][2] = b4.z; acc[r][3] = b4.w;
        }
        for (int kk = 0; kk < 128; kk += 32) {
            __syncthreads();   // previous compute / A-staging drained
            #pragma unroll
            for (int it = 0; it < 2; ++it) {
                int idx = t + it*256;
                int r = idx >> 4, c4 = idx & 15;
                *(float4*)&Ws[r][c4*4] = *(const float4*)&W[(size_t)(kk + r)*ncols + c0 + c4*4];
            }
            __syncthreads();
            #pragma unroll 8
            for (int k = 0; k < 32; ++k) {
                float4 a = *(const float4*)&As_t[kk + k][(ty*4) ^ ((k >> 2) << 3)];
                float4 w = *(const float4*)&Ws[k][tx*4];
                acc[0][0] += a.x*w.x; acc[0][1] += a.x*w.y; acc[0][2] += a.x*w.z; acc[0][3] += a.x*w.w;
                acc[1][0] += a.y*w.x; acc[1][1] += a.y*w.y; acc[1][2] += a.y*w.z; acc[1][3] += a.y*w.w;
                acc[2][0] += a.z*w.x; acc[2][1] += a.z*w.y; acc[2][2] += a.z*w.z; acc[2][3] += a.z*w.w;
                acc[3][0] += a.w*w.x; acc[3][1] += a.w*w.y; acc[3][2] += a.w*w.z; acc[3][3] += a.w*w.w;
            }
        }

        if (mode == 1 && c0 >= 128) {
            int c2 = c0 - 128;
            int tt = c2 >> 8;
            int fbase = ((c2 & 255) >> 1) + tx*2;
            unsigned* dst = kv + (size_t)tt*n_nodes*128;
            #pragma unroll
            for (int r = 0; r < 4; ++r) {
                int n = n0 + ty*4 + r;
                if (n >= n_nodes) break;
                uint2 w;
                w.x = ((unsigned)f2bf(acc[r][0]) << 16) | (unsigned)f2bf(acc[r][1]);
                w.y = ((unsigned)f2bf(acc[r][2]) << 16) | (unsigned)f2bf(acc[r][3]);
                *(uint2*)&dst[(size_t)n*128 + fbase] = w;
            }
        } else if (mode == 2) {
            #pragma unroll
            for (int r = 0; r < 4; ++r) {
                int n = n0 + ty*4 + r;
                if (n >= n_nodes) break;
                float4 hv = *(const float4*)&out0[(size_t)n*128 + c0 + tx*4];
                float4 o;
                o.x = fmaxf(g*acc[r][0] + (1.f - g)*hv.x, 0.f);
                o.y = fmaxf(g*acc[r][1] + (1.f - g)*hv.y, 0.f);
                o.z = fmaxf(g*acc[r][2] + (1.f - g)*hv.z, 0.f);
                o.w = fmaxf(g*acc[r][3] + (1.f - g)*hv.w, 0.f);
                *(float4*)&out0[(size_t)n*128 + c0 + tx*4] = o;
            }
        } else {
            #pragma unroll
            for (int r = 0; r < 4; ++r) {
                int n = n0 + ty*4 + r;
                if (n >= n_nodes) break;
                float4 o = make_float4(acc[r][0], acc[r][1], acc[r][2], acc[r][3]);
                *(float4*)&out0[(size_t)n*128 + c0 + tx*4] = o;
            }
        }
    }
}

// ---------------- fused gather attention ----------------
// 32 lanes per node (8 nodes / 256-thr block), 4 features/lane (uint4 kv load),
// online softmax (p*scale folded into k), gelu epilogue. qa in/out.
__global__ __launch_bounds__(256) void k_attn(
    const unsigned* __restrict__ srcs, const int* __restrict__ row_start,
    const uint4* __restrict__ kv, float* __restrict__ qa, int n_nodes)
{
    int lane = threadIdx.x & 31;
    int n = blockIdx.x*8 + (threadIdx.x >> 5);
    if (n >= n_nodes) return;
    float4 q4 = *(const float4*)&qa[(size_t)n*128 + lane*4];
    int s = row_start[n], e = row_start[n + 1];
    float m = -INFINITY, lsum = 0.f;
    float4 acc = make_float4(0.f, 0.f, 0.f, 0.f);

    uint4 w4n;
    if (s < e) {
        unsigned sv = srcs[s];
        w4n = kv[(((size_t)(sv >> 31))*n_nodes + (sv & 0x7fffffffu))*32 + lane];
    }
    for (int pos = s; pos < e; ) {
        uint4 w4 = w4n;
        ++pos;
        if (pos < e) {
            unsigned sv = srcs[pos];
            w4n = kv[(((size_t)(sv >> 31))*n_nodes + (sv & 0x7fffffffu))*32 + lane];
        }
        float d = __uint_as_float(w4.x & 0xffff0000u)*q4.x
                + __uint_as_float(w4.y & 0xffff0000u)*q4.y
                + __uint_as_float(w4.z & 0xffff0000u)*q4.z
                + __uint_as_float(w4.w & 0xffff0000u)*q4.w;
        d += __shfl_xor(d, 1);
        d += __shfl_xor(d, 2);
        float mn = fmaxf(m, d);
        float sc = __expf(m - mn);
        float w  = __expf(d - mn);
        lsum = lsum*sc + w;
        acc.x = acc.x*sc + w*__uint_as_float(w4.x << 16);
        acc.y = acc.y*sc + w*__uint_as_float(w4.y << 16);
        acc.z = acc.z*sc + w*__uint_as_float(w4.z << 16);
        acc.w = acc.w*sc + w*__uint_as_float(w4.w << 16);
        m = mn;
    }
    float inv = 1.f/(lsum + 1e-16f);
    float4 o;
    float x0 = acc.x*inv, x1 = acc.y*inv, x2 = acc.z*inv, x3 = acc.w*inv;
    o.x = 0.5f*x0*(1.f + erff(x0*0.70710678118654752f));
    o.y = 0.5f*x1*(1.f + erff(x1*0.70710678118654752f));
    o.z = 0.5f*x2*(1.f + erff(x2*0.70710678118654752f));
    o.w = 0.5f*x3*(1.f + erff(x3*0.70710678118654752f));
    *(float4*)&qa[(size_t)n*128 + lane*4] = o;
}

// head: one wave per node, shuffle reduce
__global__ __launch_bounds__(64) void k_head(
    const float* __restrict__ h, const float* __restrict__ hw,
    const float* __restrict__ hb, float* __restrict__ out, int n_nodes)
{
    int n = blockIdx.x;
    if (n >= n_nodes) return;
    int t = threadIdx.x;
    float h0 = h[(size_t)n*128 + t], h1 = h[(size_t)n*128 + 64 + t];
    float c0 = h0*hw[t*2]     + h1*hw[(t+64)*2];
    float c1 = h0*hw[t*2 + 1] + h1*hw[(t+64)*2 + 1];
    for (int off = 32; off > 0; off >>= 1) {
        c0 += __shfl_down(c0, off);
        c1 += __shfl_down(c1, off);
    }
    if (t == 0) {
        out[n*2]     = c0 + hb[0];
        out[n*2 + 1] = c1 + hb[1];
    }
}

extern "C" void kernel_launch(void* const* d_in, const int* in_sizes, int n_in,
                              void* d_out, int out_size, void* d_ws, size_t ws_size,
                              hipStream_t stream)
{
    const float* x      = (const float*)d_in[0];
    const int*   ef     = (const int*)d_in[1];
    const int*   er     = (const int*)d_in[2];
    const float* in_w   = (const float*)d_in[3];
    const float* in_b   = (const float*)d_in[4];
    const float* kqv_w  = (const float*)d_in[5];
    const float* kqv_b  = (const float*)d_in[6];
    const float* krel_w = (const float*)d_in[7];
    const float* vrel_w = (const float*)d_in[8];
    const float* p_rel  = (const float*)d_in[9];
    const float* out_w  = (const float*)d_in[10];
    const float* out_b  = (const float*)d_in[11];
    const float* skip   = (const float*)d_in[12];
    const float* head_w = (const float*)d_in[13];
    const float* head_b = (const float*)d_in[14];
    float* out = (float*)d_out;

    int n_nodes = in_sizes[0] / 128;
    int Ef = in_sizes[1] / 2, Er = in_sizes[2] / 2;
    int Etot = Ef + Er;
    int nch = (n_nodes + 255)/256;

    // workspace
    float* p = (float*)d_ws;
    float* h    = p; p += (size_t)n_nodes*128;
    float* qa   = p; p += (size_t)n_nodes*128;
    unsigned* kv = (unsigned*)p; p += (size_t)2*n_nodes*128;   // packed bf16 (k<<16)|v
    float* Wc   = p; p += (size_t)2*129*640;
    int* deg       = (int*)p;      p += n_nodes;
    int* csum      = (int*)p;      p += 1024;
    int* row_start = (int*)p;      p += n_nodes + 1;
    int* cursor    = (int*)p;      p += n_nodes + 1;
    unsigned* srcs = (unsigned*)p; p += Etot;

    int nb = (n_nodes + 63)/64;    // 782 blocks at 40 KB LDS -> 4 blocks/CU, one dispatch wave

    // ---- CSR build + weight compose ----
    k_zero_i<<<(n_nodes + 255)/256, 256, 0, stream>>>(deg, n_nodes);
    k_count<<<1024, 256, 0, stream>>>(ef, er, deg, Ef, Er);
    k_chunk_sums<<<nch, 256, 0, stream>>>(deg, csum, n_nodes);
    k_scan_chunks<<<1, 1024, 0, stream>>>(csum, nch);
    k_rowstart<<<(n_nodes + 256)/256, 256, 0, stream>>>(deg, csum, row_start, cursor, n_nodes);
    k_fill<<<1024, 256, 0, stream>>>(ef, er, cursor, srcs, Ef, Er);
    k_compose<<<(2*129*640 + 255)/256, 256, 0, stream>>>(kqv_w, kqv_b, krel_w, vrel_w,
                                                         p_rel, Wc);

    // ---- network ----
    k_gemm<<<nb, 256, 0, stream>>>(x, in_w, 128, in_b, h, nullptr, skip, 0, n_nodes, 0);
    for (int l = 0; l < 2; ++l) {
        const float* Wl = Wc + (size_t)l*129*640;
        k_gemm<<<nb, 256, 0, stream>>>(h, Wl, 640, Wl + 128*640, qa, kv, skip, l,
                                       n_nodes, 1);
        k_attn<<<(n_nodes + 7)/8, 256, 0, stream>>>(srcs, row_start,
                                                    (const uint4*)kv, qa, n_nodes);
        k_gemm<<<nb, 256, 0, stream>>>(qa, out_w + (size_t)l*128*128, 128,
                                       out_b + (size_t)l*128, h, nullptr, skip, l,
                                       n_nodes, 2);
    }
    k_head<<<n_nodes, 64, 0, stream>>>(h, head_w, head_b, out, n_nodes);
}

// Round 11
// 515.420 us; speedup vs baseline: 1.5225x; 1.5225x over previous
//
#include <hip/hip_runtime.h>
#include <math.h>

typedef short short8 __attribute__((ext_vector_type(8)));
typedef float f32x4 __attribute__((ext_vector_type(4)));

// ---------------- helpers ----------------
__device__ __forceinline__ unsigned short f2bf(float f){   // RTN bf16
    unsigned u = __float_as_uint(f);
    unsigned r = u + 0x7fffu + ((u >> 16) & 1u);
    return (unsigned short)(r >> 16);
}

// ---------------- CSR build ----------------
__global__ void k_zero_i(int* __restrict__ p, int n)
{
    for (int i = blockIdx.x*blockDim.x + threadIdx.x; i < n; i += gridDim.x*blockDim.x)
        p[i] = 0;
}

__global__ void k_count(const int* __restrict__ ef, const int* __restrict__ er,
                        int* __restrict__ deg, int Ef, int Er)
{
    int Etot = Ef + Er;
    for (int e = blockIdx.x*blockDim.x + threadIdx.x; e < Etot; e += gridDim.x*blockDim.x) {
        int dst = (e < Ef) ? ef[Ef + e] : er[Er + (e - Ef)];
        atomicAdd(&deg[dst], 1);
    }
}

__global__ void k_chunk_sums(const int* __restrict__ deg, int* __restrict__ csum, int n)
{
    __shared__ int s[256];
    int t = threadIdx.x, i = blockIdx.x*256 + t;
    s[t] = (i < n) ? deg[i] : 0;
    __syncthreads();
    for (int off = 128; off > 0; off >>= 1) {
        if (t < off) s[t] += s[t + off];
        __syncthreads();
    }
    if (t == 0) csum[blockIdx.x] = s[0];
}

__global__ void k_scan_chunks(int* __restrict__ csum, int nch)
{
    __shared__ int s[1024];
    int t = threadIdx.x;
    int v = (t < nch) ? csum[t] : 0;
    s[t] = v; __syncthreads();
    for (int off = 1; off < 1024; off <<= 1) {
        int u = (t >= off) ? s[t - off] : 0;
        __syncthreads();
        s[t] += u;
        __syncthreads();
    }
    if (t < nch) csum[t] = s[t] - v;
}

__global__ void k_rowstart(const int* __restrict__ deg, const int* __restrict__ csum,
                           int* __restrict__ row_start, int* __restrict__ cursor, int n)
{
    __shared__ int s[256];
    int t = threadIdx.x, i = blockIdx.x*256 + t;
    int d = (i < n) ? deg[i] : 0;
    s[t] = d; __syncthreads();
    for (int off = 1; off < 256; off <<= 1) {
        int u = (t >= off) ? s[t - off] : 0;
        __syncthreads();
        s[t] += u;
        __syncthreads();
    }
    if (i <= n) {
        int rs = csum[blockIdx.x] + s[t] - d;   // exclusive
        row_start[i] = rs;
        cursor[i] = rs;
    }
}

__global__ void k_fill(const int* __restrict__ ef, const int* __restrict__ er,
                       int* __restrict__ cursor, unsigned* __restrict__ srcs,
                       int Ef, int Er)
{
    int Etot = Ef + Er;
    for (int e = blockIdx.x*blockDim.x + threadIdx.x; e < Etot; e += gridDim.x*blockDim.x) {
        int src, dst; unsigned tbit;
        if (e < Ef) { src = ef[e]; dst = ef[Ef + e]; tbit = 0u; }
        else { int e2 = e - Ef; src = er[e2]; dst = er[Er + e2]; tbit = 0x80000000u; }
        int pos = atomicAdd(&cursor[dst], 1);
        srcs[pos] = (unsigned)src | tbit;
    }
}

// ---------------- composed weights (transposed, bf16) ----------------
// WcT[l][c][k]: c in [0,640): 0-127 q; 128+tt*256+2f = krel(f) (p*scale folded);
// +2f+1 = vrel(f). biasc[l][c] f32.
__global__ void k_compose(const float* __restrict__ kqv_w, const float* __restrict__ kqv_b,
                          const float* __restrict__ krel_w, const float* __restrict__ vrel_w,
                          const float* __restrict__ p_rel, unsigned short* __restrict__ WcT,
                          float* __restrict__ biasc)
{
    int idx = blockIdx.x*blockDim.x + threadIdx.x;
    int tot = 2*129*640;
    if (idx >= tot) return;
    int l = idx / (129*640);
    int rem = idx % (129*640);
    int r = rem / 640, c = rem % 640;
    float val;
    if (c < 128) {
        val = (r < 128) ? kqv_w[((size_t)l*128 + r)*384 + 128 + c]
                        : kqv_b[l*384 + 128 + c];
    } else {
        int c2 = c - 128;
        int tt = c2 >> 8;
        int cc = c2 & 255;
        int f = cc >> 1;
        int part = cc & 1;             // 0 = k, 1 = v
        int hh = f >> 4, fd = f & 15;
        const float* rw = (part == 0 ? krel_w : vrel_w)
                          + (((size_t)(l*2 + tt)*8 + hh)*16)*16 + fd;
        int base_col = (part == 0 ? 0 : 256) + hh*16;
        float s = 0.f;
        #pragma unroll
        for (int d = 0; d < 16; ++d) {
            float a = (r < 128) ? kqv_w[((size_t)l*128 + r)*384 + base_col + d]
                                : kqv_b[l*384 + base_col + d];
            s += a * rw[d*16];
        }
        if (part == 0) s *= p_rel[(l*2 + tt)*8 + hh] * 0.25f;
        val = s;
    }
    if (r < 128) WcT[((size_t)l*640 + c)*128 + r] = f2bf(val);
    else         biasc[l*640 + c] = val;
}

// ---------------- MFMA kqv GEMM ----------------
// C[n, 0:640] = h[n, 0:128](bf16) @ WcT^T(bf16) + biasc, f32 accum via
// mfma_f32_16x16x32_bf16. Block: 64 rows x 64 cols, 4 waves (16 cols each,
// 4 M-tiles). Tiles staged as 8-bf16 granules, XOR swizzled (g ^ (row&15)).
// Grid XCD-swizzled: same row tile -> same XCD (L2 reuse of A).
__global__ __launch_bounds__(256) void k_kqv_mfma(
    const float* __restrict__ h, const unsigned short* __restrict__ WcT,
    const float* __restrict__ biasc, float* __restrict__ qa,
    unsigned* __restrict__ kv, int n_nodes, int R, int C)
{
    __shared__ uint4 As[64*16];    // 16 KB bf16 A tile
    __shared__ uint4 Ws[64*16];    // 16 KB bf16 W tile (rows = output cols)
    int b = blockIdx.x;
    int xcd = b & 7, jj = b >> 3;
    int r_t = (jj / C)*8 + xcd;
    int c_t = jj % C;
    if (r_t >= R) return;
    int n0 = r_t*64, c0 = c_t*64;
    int t = threadIdx.x;

    // stage A: h rows -> bf16 granules
    #pragma unroll
    for (int it = 0; it < 4; ++it) {
        int gi = t + it*256;               // [0,1024)
        int m = gi >> 4, g = gi & 15;
        int n = n0 + m;
        float4 a0 = make_float4(0.f,0.f,0.f,0.f), a1 = a0;
        if (n < n_nodes) {
            a0 = *(const float4*)&h[(size_t)n*128 + g*8];
            a1 = *(const float4*)&h[(size_t)n*128 + g*8 + 4];
        }
        uint4 wd;
        wd.x = (unsigned)f2bf(a0.x) | ((unsigned)f2bf(a0.y) << 16);
        wd.y = (unsigned)f2bf(a0.z) | ((unsigned)f2bf(a0.w) << 16);
        wd.z = (unsigned)f2bf(a1.x) | ((unsigned)f2bf(a1.y) << 16);
        wd.w = (unsigned)f2bf(a1.z) | ((unsigned)f2bf(a1.w) << 16);
        As[m*16 + (g ^ (m & 15))] = wd;
    }
    // stage W: WcT rows c0..c0+63 (already bf16)
    #pragma unroll
    for (int it = 0; it < 4; ++it) {
        int gi = t + it*256;
        int cw = gi >> 4, g = gi & 15;
        uint4 wv = *(const uint4*)&WcT[((size_t)(c0 + cw))*128 + g*8];
        Ws[cw*16 + (g ^ (cw & 15))] = wv;
    }
    __syncthreads();

    int lane = t & 63, w = t >> 6;
    int lm = lane & 15, quad = lane >> 4;
    f32x4 acc[4];
    #pragma unroll
    for (int i = 0; i < 4; ++i) { acc[i][0]=0.f; acc[i][1]=0.f; acc[i][2]=0.f; acc[i][3]=0.f; }

    #pragma unroll
    for (int chunk = 0; chunk < 4; ++chunk) {
        int gq = chunk*4 + quad;
        short8 bfrag = *(const short8*)&Ws[(w*16 + lm)*16 + (gq ^ lm)];
        #pragma unroll
        for (int i = 0; i < 4; ++i) {
            short8 afrag = *(const short8*)&As[(i*16 + lm)*16 + (gq ^ lm)];
            acc[i] = __builtin_amdgcn_mfma_f32_16x16x32_bf16(afrag, bfrag, acc[i], 0, 0, 0);
        }
    }

    int c = c0 + w*16 + lm;
    float bc = biasc[c];
    if (c0 < 128) {                        // q columns: f32 store
        #pragma unroll
        for (int i = 0; i < 4; ++i) {
            #pragma unroll
            for (int rr = 0; rr < 4; ++rr) {
                int m = n0 + i*16 + quad*4 + rr;
                if (m < n_nodes) qa[(size_t)m*128 + c] = acc[i][rr] + bc;
            }
        }
    } else {                               // kv columns: pack bf16 (k<<16)|v via shfl pair
        int c2 = c - 128;
        int tt = c2 >> 8;
        int f = (c2 & 255) >> 1;
        unsigned* dst = kv + (size_t)tt*n_nodes*128;
        bool isk = (lane & 1) == 0;        // even col = k, partner lane holds v
        #pragma unroll
        for (int i = 0; i < 4; ++i) {
            #pragma unroll
            for (int rr = 0; rr < 4; ++rr) {
                float val = acc[i][rr] + bc;
                float other = __shfl_xor(val, 1);
                int m = n0 + i*16 + quad*4 + rr;
                if (isk && m < n_nodes) {
                    unsigned wd = ((unsigned)f2bf(val) << 16) | (unsigned)f2bf(other);
                    dst[(size_t)m*128 + f] = wd;
                }
            }
        }
    }
}

// ---------------- f32 tiled GEMM (in_proj / out_proj), r9 structure ----------------
// BM=64, BN=64, BK=32; 256 threads; 4x4 register tile; XOR-swizzled A_t.
// mode 0: plain store; mode 2: h = relu(g*C + (1-g)*h)
__global__ __launch_bounds__(256) void k_gemm(
    const float* __restrict__ A, const float* __restrict__ W, int ldw,
    const float* __restrict__ bias, float* __restrict__ out0,
    const float* __restrict__ skip, int l,
    int n_nodes, int ncol_tiles, int mode)
{
    __shared__ float As_t[32][64];
    __shared__ float Ws[32][64];
    int tile_n = blockIdx.x / ncol_tiles;
    int tile_c = blockIdx.x % ncol_tiles;
    int n0 = tile_n*64, c0 = tile_c*64;
    int t = threadIdx.x, tx = t & 15, ty = t >> 4;

    float4 b4 = *(const float4*)&bias[c0 + tx*4];
    float acc[4][4];
    #pragma unroll
    for (int r = 0; r < 4; ++r) {
        acc[r][0] = b4.x; acc[r][1] = b4.y; acc[r][2] = b4.z; acc[r][3] = b4.w;
    }

    for (int kk = 0; kk < 128; kk += 32) {
        __syncthreads();
        #pragma unroll
        for (int it = 0; it < 2; ++it) {
            int idx = t + it*256;
            int m = idx >> 3, c4 = idx & 7;
            int n = n0 + m;
            float4 a = make_float4(0.f, 0.f, 0.f, 0.f);
            if (n < n_nodes) a = *(const float4*)&A[(size_t)n*128 + kk + c4*4];
            int col = m ^ (c4 << 3);
            As_t[c4*4 + 0][col] = a.x;
            As_t[c4*4 + 1][col] = a.y;
            As_t[c4*4 + 2][col] = a.z;
            As_t[c4*4 + 3][col] = a.w;
        }
        #pragma unroll
        for (int it = 0; it < 2; ++it) {
            int idx = t + it*256;
            int r = idx >> 4, c4 = idx & 15;
            *(float4*)&Ws[r][c4*4] = *(const float4*)&W[(size_t)(kk + r)*ldw + c0 + c4*4];
        }
        __syncthreads();
        #pragma unroll 8
        for (int k = 0; k < 32; ++k) {
            float4 a = *(const float4*)&As_t[k][(ty*4) ^ ((k >> 2) << 3)];
            float4 w = *(const float4*)&Ws[k][tx*4];
            acc[0][0] += a.x*w.x; acc[0][1] += a.x*w.y; acc[0][2] += a.x*w.z; acc[0][3] += a.x*w.w;
            acc[1][0] += a.y*w.x; acc[1][1] += a.y*w.y; acc[1][2] += a.y*w.z; acc[1][3] += a.y*w.w;
            acc[2][0] += a.z*w.x; acc[2][1] += a.z*w.y; acc[2][2] += a.z*w.z; acc[2][3] += a.z*w.w;
            acc[3][0] += a.w*w.x; acc[3][1] += a.w*w.y; acc[3][2] += a.w*w.z; acc[3][3] += a.w*w.w;
        }
    }

    if (mode == 2) {
        float g = 1.f/(1.f + expf(-skip[l]));
        #pragma unroll
        for (int r = 0; r < 4; ++r) {
            int n = n0 + ty*4 + r;
            if (n >= n_nodes) break;
            float4 hv = *(const float4*)&out0[(size_t)n*128 + c0 + tx*4];
            float4 o;
            o.x = fmaxf(g*acc[r][0] + (1.f - g)*hv.x, 0.f);
            o.y = fmaxf(g*acc[r][1] + (1.f - g)*hv.y, 0.f);
            o.z = fmaxf(g*acc[r][2] + (1.f - g)*hv.z, 0.f);
            o.w = fmaxf(g*acc[r][3] + (1.f - g)*hv.w, 0.f);
            *(float4*)&out0[(size_t)n*128 + c0 + tx*4] = o;
        }
    } else {
        #pragma unroll
        for (int r = 0; r < 4; ++r) {
            int n = n0 + ty*4 + r;
            if (n >= n_nodes) break;
            float4 o = make_float4(acc[r][0], acc[r][1], acc[r][2], acc[r][3]);
            *(float4*)&out0[(size_t)n*128 + c0 + tx*4] = o;
        }
    }
}

// ---------------- fused gather attention ----------------
__global__ __launch_bounds__(256) void k_attn(
    const unsigned* __restrict__ srcs, const int* __restrict__ row_start,
    const uint4* __restrict__ kv, float* __restrict__ qa, int n_nodes)
{
    int lane = threadIdx.x & 31;
    int n = blockIdx.x*8 + (threadIdx.x >> 5);
    if (n >= n_nodes) return;
    float4 q4 = *(const float4*)&qa[(size_t)n*128 + lane*4];
    int s = row_start[n], e = row_start[n + 1];
    float m = -INFINITY, lsum = 0.f;
    float4 acc = make_float4(0.f, 0.f, 0.f, 0.f);

    uint4 w4n;
    if (s < e) {
        unsigned sv = srcs[s];
        w4n = kv[(((size_t)(sv >> 31))*n_nodes + (sv & 0x7fffffffu))*32 + lane];
    }
    for (int pos = s; pos < e; ) {
        uint4 w4 = w4n;
        ++pos;
        if (pos < e) {
            unsigned sv = srcs[pos];
            w4n = kv[(((size_t)(sv >> 31))*n_nodes + (sv & 0x7fffffffu))*32 + lane];
        }
        float d = __uint_as_float(w4.x & 0xffff0000u)*q4.x
                + __uint_as_float(w4.y & 0xffff0000u)*q4.y
                + __uint_as_float(w4.z & 0xffff0000u)*q4.z
                + __uint_as_float(w4.w & 0xffff0000u)*q4.w;
        d += __shfl_xor(d, 1);
        d += __shfl_xor(d, 2);
        float mn = fmaxf(m, d);
        float sc = __expf(m - mn);
        float w  = __expf(d - mn);
        lsum = lsum*sc + w;
        acc.x = acc.x*sc + w*__uint_as_float(w4.x << 16);
        acc.y = acc.y*sc + w*__uint_as_float(w4.y << 16);
        acc.z = acc.z*sc + w*__uint_as_float(w4.z << 16);
        acc.w = acc.w*sc + w*__uint_as_float(w4.w << 16);
        m = mn;
    }
    float inv = 1.f/(lsum + 1e-16f);
    float4 o;
    float x0 = acc.x*inv, x1 = acc.y*inv, x2 = acc.z*inv, x3 = acc.w*inv;
    o.x = 0.5f*x0*(1.f + erff(x0*0.70710678118654752f));
    o.y = 0.5f*x1*(1.f + erff(x1*0.70710678118654752f));
    o.z = 0.5f*x2*(1.f + erff(x2*0.70710678118654752f));
    o.w = 0.5f*x3*(1.f + erff(x3*0.70710678118654752f));
    *(float4*)&qa[(size_t)n*128 + lane*4] = o;
}

// head: one wave per node, shuffle reduce
__global__ __launch_bounds__(64) void k_head(
    const float* __restrict__ h, const float* __restrict__ hw,
    const float* __restrict__ hb, float* __restrict__ out, int n_nodes)
{
    int n = blockIdx.x;
    if (n >= n_nodes) return;
    int t = threadIdx.x;
    float h0 = h[(size_t)n*128 + t], h1 = h[(size_t)n*128 + 64 + t];
    float c0 = h0*hw[t*2]     + h1*hw[(t+64)*2];
    float c1 = h0*hw[t*2 + 1] + h1*hw[(t+64)*2 + 1];
    for (int off = 32; off > 0; off >>= 1) {
        c0 += __shfl_down(c0, off);
        c1 += __shfl_down(c1, off);
    }
    if (t == 0) {
        out[n*2]     = c0 + hb[0];
        out[n*2 + 1] = c1 + hb[1];
    }
}

extern "C" void kernel_launch(void* const* d_in, const int* in_sizes, int n_in,
                              void* d_out, int out_size, void* d_ws, size_t ws_size,
                              hipStream_t stream)
{
    const float* x      = (const float*)d_in[0];
    const int*   ef     = (const int*)d_in[1];
    const int*   er     = (const int*)d_in[2];
    const float* in_w   = (const float*)d_in[3];
    const float* in_b   = (const float*)d_in[4];
    const float* kqv_w  = (const float*)d_in[5];
    const float* kqv_b  = (const float*)d_in[6];
    const float* krel_w = (const float*)d_in[7];
    const float* vrel_w = (const float*)d_in[8];
    const float* p_rel  = (const float*)d_in[9];
    const float* out_w  = (const float*)d_in[10];
    const float* out_b  = (const float*)d_in[11];
    const float* skip   = (const float*)d_in[12];
    const float* head_w = (const float*)d_in[13];
    const float* head_b = (const float*)d_in[14];
    float* out = (float*)d_out;

    int n_nodes = in_sizes[0] / 128;
    int Ef = in_sizes[1] / 2, Er = in_sizes[2] / 2;
    int Etot = Ef + Er;
    int nch = (n_nodes + 255)/256;

    // workspace
    float* p = (float*)d_ws;
    float* h    = p; p += (size_t)n_nodes*128;
    float* qa   = p; p += (size_t)n_nodes*128;
    unsigned* kv = (unsigned*)p; p += (size_t)2*n_nodes*128;   // packed bf16 (k<<16)|v
    unsigned short* WcT = (unsigned short*)p; p += (size_t)(2*640*128)/2;  // bf16
    float* biasc = p; p += 2*640;
    int* deg       = (int*)p;      p += n_nodes;
    int* csum      = (int*)p;      p += 1024;
    int* row_start = (int*)p;      p += n_nodes + 1;
    int* cursor    = (int*)p;      p += n_nodes + 1;
    unsigned* srcs = (unsigned*)p; p += Etot;

    int ntile = (n_nodes + 63)/64;               // row tiles (R)
    int Rg = (ntile + 7)/8;
    int mfma_grid = Rg*8*10;                     // XCD-swizzled 2-D grid

    // ---- CSR build + weight compose ----
    k_zero_i<<<(n_nodes + 255)/256, 256, 0, stream>>>(deg, n_nodes);
    k_count<<<1024, 256, 0, stream>>>(ef, er, deg, Ef, Er);
    k_chunk_sums<<<nch, 256, 0, stream>>>(deg, csum, n_nodes);
    k_scan_chunks<<<1, 1024, 0, stream>>>(csum, nch);
    k_rowstart<<<(n_nodes + 256)/256, 256, 0, stream>>>(deg, csum, row_start, cursor, n_nodes);
    k_fill<<<1024, 256, 0, stream>>>(ef, er, cursor, srcs, Ef, Er);
    k_compose<<<(2*129*640 + 255)/256, 256, 0, stream>>>(kqv_w, kqv_b, krel_w, vrel_w,
                                                         p_rel, WcT, biasc);

    // ---- network ----
    k_gemm<<<ntile*2, 256, 0, stream>>>(x, in_w, 128, in_b, h, skip, 0, n_nodes, 2, 0);
    for (int l = 0; l < 2; ++l) {
        k_kqv_mfma<<<mfma_grid, 256, 0, stream>>>(h, WcT + (size_t)l*640*128,
                                                  biasc + l*640, qa, kv,
                                                  n_nodes, ntile, 10);
        k_attn<<<(n_nodes + 7)/8, 256, 0, stream>>>(srcs, row_start,
                                                    (const uint4*)kv, qa, n_nodes);
        k_gemm<<<ntile*2, 256, 0, stream>>>(qa, out_w + (size_t)l*128*128, 128,
                                            out_b + (size_t)l*128, h, skip, l,
                                            n_nodes, 2, 2);
    }
    k_head<<<n_nodes, 64, 0, stream>>>(h, head_w, head_b, out, n_nodes);
}

// Round 12
// 496.770 us; speedup vs baseline: 1.5797x; 1.0375x over previous
//
#include <hip/hip_runtime.h>
#include <math.h>

typedef short short8 __attribute__((ext_vector_type(8)));
typedef float f32x4 __attribute__((ext_vector_type(4)));

// ---------------- helpers ----------------
__device__ __forceinline__ unsigned short f2bf(float f){   // RTN bf16
    unsigned u = __float_as_uint(f);
    unsigned r = u + 0x7fffu + ((u >> 16) & 1u);
    return (unsigned short)(r >> 16);
}

// ---------------- CSR build ----------------
__global__ void k_zero_i(int* __restrict__ p, int n)
{
    for (int i = blockIdx.x*blockDim.x + threadIdx.x; i < n; i += gridDim.x*blockDim.x)
        p[i] = 0;
}

__global__ void k_count(const int* __restrict__ ef, const int* __restrict__ er,
                        int* __restrict__ deg, int Ef, int Er)
{
    int Etot = Ef + Er;
    for (int e = blockIdx.x*blockDim.x + threadIdx.x; e < Etot; e += gridDim.x*blockDim.x) {
        int dst = (e < Ef) ? ef[Ef + e] : er[Er + (e - Ef)];
        atomicAdd(&deg[dst], 1);
    }
}

__global__ void k_chunk_sums(const int* __restrict__ deg, int* __restrict__ csum, int n)
{
    __shared__ int s[256];
    int t = threadIdx.x, i = blockIdx.x*256 + t;
    s[t] = (i < n) ? deg[i] : 0;
    __syncthreads();
    for (int off = 128; off > 0; off >>= 1) {
        if (t < off) s[t] += s[t + off];
        __syncthreads();
    }
    if (t == 0) csum[blockIdx.x] = s[0];
}

__global__ void k_scan_chunks(int* __restrict__ csum, int nch)
{
    __shared__ int s[1024];
    int t = threadIdx.x;
    int v = (t < nch) ? csum[t] : 0;
    s[t] = v; __syncthreads();
    for (int off = 1; off < 1024; off <<= 1) {
        int u = (t >= off) ? s[t - off] : 0;
        __syncthreads();
        s[t] += u;
        __syncthreads();
    }
    if (t < nch) csum[t] = s[t] - v;
}

__global__ void k_rowstart(const int* __restrict__ deg, const int* __restrict__ csum,
                           int* __restrict__ row_start, int* __restrict__ cursor, int n)
{
    __shared__ int s[256];
    int t = threadIdx.x, i = blockIdx.x*256 + t;
    int d = (i < n) ? deg[i] : 0;
    s[t] = d; __syncthreads();
    for (int off = 1; off < 256; off <<= 1) {
        int u = (t >= off) ? s[t - off] : 0;
        __syncthreads();
        s[t] += u;
        __syncthreads();
    }
    if (i <= n) {
        int rs = csum[blockIdx.x] + s[t] - d;   // exclusive
        row_start[i] = rs;
        cursor[i] = rs;
    }
}

__global__ void k_fill(const int* __restrict__ ef, const int* __restrict__ er,
                       int* __restrict__ cursor, unsigned* __restrict__ srcs,
                       int Ef, int Er)
{
    int Etot = Ef + Er;
    for (int e = blockIdx.x*blockDim.x + threadIdx.x; e < Etot; e += gridDim.x*blockDim.x) {
        int src, dst; unsigned tbit;
        if (e < Ef) { src = ef[e]; dst = ef[Ef + e]; tbit = 0u; }
        else { int e2 = e - Ef; src = er[e2]; dst = er[Er + e2]; tbit = 0x80000000u; }
        int pos = atomicAdd(&cursor[dst], 1);
        srcs[pos] = (unsigned)src | tbit;
    }
}

// ---------------- composed kqv weights (transposed, bf16) ----------------
__global__ void k_compose(const float* __restrict__ kqv_w, const float* __restrict__ kqv_b,
                          const float* __restrict__ krel_w, const float* __restrict__ vrel_w,
                          const float* __restrict__ p_rel, unsigned short* __restrict__ WcT,
                          float* __restrict__ biasc)
{
    int idx = blockIdx.x*blockDim.x + threadIdx.x;
    int tot = 2*129*640;
    if (idx >= tot) return;
    int l = idx / (129*640);
    int rem = idx % (129*640);
    int r = rem / 640, c = rem % 640;
    float val;
    if (c < 128) {
        val = (r < 128) ? kqv_w[((size_t)l*128 + r)*384 + 128 + c]
                        : kqv_b[l*384 + 128 + c];
    } else {
        int c2 = c - 128;
        int tt = c2 >> 8;
        int cc = c2 & 255;
        int f = cc >> 1;
        int part = cc & 1;             // 0 = k, 1 = v
        int hh = f >> 4, fd = f & 15;
        const float* rw = (part == 0 ? krel_w : vrel_w)
                          + (((size_t)(l*2 + tt)*8 + hh)*16)*16 + fd;
        int base_col = (part == 0 ? 0 : 256) + hh*16;
        float s = 0.f;
        #pragma unroll
        for (int d = 0; d < 16; ++d) {
            float a = (r < 128) ? kqv_w[((size_t)l*128 + r)*384 + base_col + d]
                                : kqv_b[l*384 + base_col + d];
            s += a * rw[d*16];
        }
        if (part == 0) s *= p_rel[(l*2 + tt)*8 + hh] * 0.25f;
        val = s;
    }
    if (r < 128) WcT[((size_t)l*640 + c)*128 + r] = f2bf(val);
    else         biasc[l*640 + c] = val;
}

// out_w -> transposed bf16 WoT[l][c][k], biaso = out_b
__global__ void k_compose_out(const float* __restrict__ out_w, const float* __restrict__ out_b,
                              unsigned short* __restrict__ WoT, float* __restrict__ biaso)
{
    int idx = blockIdx.x*blockDim.x + threadIdx.x;
    int tot = 2*129*128;
    if (idx >= tot) return;
    int l = idx / (129*128);
    int rem = idx % (129*128);
    int r = rem / 128, c = rem % 128;
    if (r < 128) WoT[((size_t)l*128 + c)*128 + r] = f2bf(out_w[((size_t)l*128 + r)*128 + c]);
    else         biaso[l*128 + c] = out_b[l*128 + c];
}

// ---------------- unified MFMA GEMM (bf16 in, f32 accum) ----------------
// mode 1 (kqv): cols<128 q f32 -> out0; cols>=128 packed bf16 kv
// mode 2 (out_proj): out0 = relu(g*C + (1-g)*out0)
__global__ __launch_bounds__(256) void k_mfma(
    const float* __restrict__ A, const unsigned short* __restrict__ WT,
    const float* __restrict__ biasc, float* __restrict__ out0,
    unsigned* __restrict__ kv, const float* __restrict__ skip, int l,
    int n_nodes, int R, int C, int mode)
{
    __shared__ uint4 As[64*16];    // 16 KB bf16 A tile
    __shared__ uint4 Ws[64*16];    // 16 KB bf16 W tile (rows = output cols)
    int b = blockIdx.x;
    int xcd = b & 7, jj = b >> 3;
    int r_t = (jj / C)*8 + xcd;
    int c_t = jj % C;
    if (r_t >= R) return;
    int n0 = r_t*64, c0 = c_t*64;
    int t = threadIdx.x;

    #pragma unroll
    for (int it = 0; it < 4; ++it) {
        int gi = t + it*256;               // [0,1024)
        int m = gi >> 4, g = gi & 15;
        int n = n0 + m;
        float4 a0 = make_float4(0.f,0.f,0.f,0.f), a1 = a0;
        if (n < n_nodes) {
            a0 = *(const float4*)&A[(size_t)n*128 + g*8];
            a1 = *(const float4*)&A[(size_t)n*128 + g*8 + 4];
        }
        uint4 wd;
        wd.x = (unsigned)f2bf(a0.x) | ((unsigned)f2bf(a0.y) << 16);
        wd.y = (unsigned)f2bf(a0.z) | ((unsigned)f2bf(a0.w) << 16);
        wd.z = (unsigned)f2bf(a1.x) | ((unsigned)f2bf(a1.y) << 16);
        wd.w = (unsigned)f2bf(a1.z) | ((unsigned)f2bf(a1.w) << 16);
        As[m*16 + (g ^ (m & 15))] = wd;
    }
    #pragma unroll
    for (int it = 0; it < 4; ++it) {
        int gi = t + it*256;
        int cw = gi >> 4, g = gi & 15;
        uint4 wv = *(const uint4*)&WT[((size_t)(c0 + cw))*128 + g*8];
        Ws[cw*16 + (g ^ (cw & 15))] = wv;
    }
    __syncthreads();

    int lane = t & 63, w = t >> 6;
    int lm = lane & 15, quad = lane >> 4;
    f32x4 acc[4];
    #pragma unroll
    for (int i = 0; i < 4; ++i) { acc[i][0]=0.f; acc[i][1]=0.f; acc[i][2]=0.f; acc[i][3]=0.f; }

    #pragma unroll
    for (int chunk = 0; chunk < 4; ++chunk) {
        int gq = chunk*4 + quad;
        short8 bfrag = *(const short8*)&Ws[(w*16 + lm)*16 + (gq ^ lm)];
        #pragma unroll
        for (int i = 0; i < 4; ++i) {
            short8 afrag = *(const short8*)&As[(i*16 + lm)*16 + (gq ^ lm)];
            acc[i] = __builtin_amdgcn_mfma_f32_16x16x32_bf16(afrag, bfrag, acc[i], 0, 0, 0);
        }
    }

    int c = c0 + w*16 + lm;
    float bc = biasc[c];
    if (mode == 2) {
        float g = 1.f/(1.f + expf(-skip[l]));
        #pragma unroll
        for (int i = 0; i < 4; ++i) {
            #pragma unroll
            for (int rr = 0; rr < 4; ++rr) {
                int m = n0 + i*16 + quad*4 + rr;
                if (m < n_nodes) {
                    size_t o = (size_t)m*128 + c;
                    float hv = out0[o];
                    out0[o] = fmaxf(g*(acc[i][rr] + bc) + (1.f - g)*hv, 0.f);
                }
            }
        }
    } else if (c0 < 128) {                 // q columns: f32 store
        #pragma unroll
        for (int i = 0; i < 4; ++i) {
            #pragma unroll
            for (int rr = 0; rr < 4; ++rr) {
                int m = n0 + i*16 + quad*4 + rr;
                if (m < n_nodes) out0[(size_t)m*128 + c] = acc[i][rr] + bc;
            }
        }
    } else {                               // kv columns: pack bf16 (k<<16)|v via shfl pair
        int c2 = c - 128;
        int tt = c2 >> 8;
        int f = (c2 & 255) >> 1;
        unsigned* dst = kv + (size_t)tt*n_nodes*128;
        bool isk = (lane & 1) == 0;
        #pragma unroll
        for (int i = 0; i < 4; ++i) {
            #pragma unroll
            for (int rr = 0; rr < 4; ++rr) {
                float val = acc[i][rr] + bc;
                float other = __shfl_xor(val, 1);
                int m = n0 + i*16 + quad*4 + rr;
                if (isk && m < n_nodes) {
                    unsigned wd = ((unsigned)f2bf(val) << 16) | (unsigned)f2bf(other);
                    dst[(size_t)m*128 + f] = wd;
                }
            }
        }
    }
}

// ---------------- f32 tiled GEMM (in_proj only) ----------------
__global__ __launch_bounds__(256) void k_gemm(
    const float* __restrict__ A, const float* __restrict__ W, int ldw,
    const float* __restrict__ bias, float* __restrict__ out0,
    int n_nodes, int ncol_tiles)
{
    __shared__ float As_t[32][64];
    __shared__ float Ws[32][64];
    int tile_n = blockIdx.x / ncol_tiles;
    int tile_c = blockIdx.x % ncol_tiles;
    int n0 = tile_n*64, c0 = tile_c*64;
    int t = threadIdx.x, tx = t & 15, ty = t >> 4;

    float4 b4 = *(const float4*)&bias[c0 + tx*4];
    float acc[4][4];
    #pragma unroll
    for (int r = 0; r < 4; ++r) {
        acc[r][0] = b4.x; acc[r][1] = b4.y; acc[r][2] = b4.z; acc[r][3] = b4.w;
    }

    for (int kk = 0; kk < 128; kk += 32) {
        __syncthreads();
        #pragma unroll
        for (int it = 0; it < 2; ++it) {
            int idx = t + it*256;
            int m = idx >> 3, c4 = idx & 7;
            int n = n0 + m;
            float4 a = make_float4(0.f, 0.f, 0.f, 0.f);
            if (n < n_nodes) a = *(const float4*)&A[(size_t)n*128 + kk + c4*4];
            int col = m ^ (c4 << 3);
            As_t[c4*4 + 0][col] = a.x;
            As_t[c4*4 + 1][col] = a.y;
            As_t[c4*4 + 2][col] = a.z;
            As_t[c4*4 + 3][col] = a.w;
        }
        #pragma unroll
        for (int it = 0; it < 2; ++it) {
            int idx = t + it*256;
            int r = idx >> 4, c4 = idx & 15;
            *(float4*)&Ws[r][c4*4] = *(const float4*)&W[(size_t)(kk + r)*ldw + c0 + c4*4];
        }
        __syncthreads();
        #pragma unroll 8
        for (int k = 0; k < 32; ++k) {
            float4 a = *(const float4*)&As_t[k][(ty*4) ^ ((k >> 2) << 3)];
            float4 w = *(const float4*)&Ws[k][tx*4];
            acc[0][0] += a.x*w.x; acc[0][1] += a.x*w.y; acc[0][2] += a.x*w.z; acc[0][3] += a.x*w.w;
            acc[1][0] += a.y*w.x; acc[1][1] += a.y*w.y; acc[1][2] += a.y*w.z; acc[1][3] += a.y*w.w;
            acc[2][0] += a.z*w.x; acc[2][1] += a.z*w.y; acc[2][2] += a.z*w.z; acc[2][3] += a.z*w.w;
            acc[3][0] += a.w*w.x; acc[3][1] += a.w*w.y; acc[3][2] += a.w*w.z; acc[3][3] += a.w*w.w;
        }
    }

    #pragma unroll
    for (int r = 0; r < 4; ++r) {
        int n = n0 + ty*4 + r;
        if (n >= n_nodes) break;
        float4 o = make_float4(acc[r][0], acc[r][1], acc[r][2], acc[r][3]);
        *(float4*)&out0[(size_t)n*128 + c0 + tx*4] = o;
    }
}

// ---------------- fused gather attention: 2-state unrolled online softmax ----------------
__global__ __launch_bounds__(256) void k_attn(
    const unsigned* __restrict__ srcs, const int* __restrict__ row_start,
    const uint4* __restrict__ kv, float* __restrict__ qa, int n_nodes)
{
    int lane = threadIdx.x & 31;
    int n = blockIdx.x*8 + (threadIdx.x >> 5);
    if (n >= n_nodes) return;
    float4 q4 = *(const float4*)&qa[(size_t)n*128 + lane*4];
    int s = row_start[n], e = row_start[n + 1];

    float m0 = -INFINITY, l0 = 0.f; float4 a0 = make_float4(0.f,0.f,0.f,0.f);
    float m1 = -INFINITY, l1 = 0.f; float4 a1 = make_float4(0.f,0.f,0.f,0.f);

    uint4 w0n, w1n;
    if (s < e) {
        unsigned sv = srcs[s];
        w0n = kv[(((size_t)(sv >> 31))*n_nodes + (sv & 0x7fffffffu))*32 + lane];
    }
    if (s + 1 < e) {
        unsigned sv = srcs[s + 1];
        w1n = kv[(((size_t)(sv >> 31))*n_nodes + (sv & 0x7fffffffu))*32 + lane];
    }
    int pos = s;
    for (; pos + 1 < e; pos += 2) {
        uint4 w0 = w0n, w1 = w1n;
        if (pos + 2 < e) {
            unsigned sv = srcs[pos + 2];
            w0n = kv[(((size_t)(sv >> 31))*n_nodes + (sv & 0x7fffffffu))*32 + lane];
        }
        if (pos + 3 < e) {
            unsigned sv = srcs[pos + 3];
            w1n = kv[(((size_t)(sv >> 31))*n_nodes + (sv & 0x7fffffffu))*32 + lane];
        }
        float d0 = __uint_as_float(w0.x & 0xffff0000u)*q4.x
                 + __uint_as_float(w0.y & 0xffff0000u)*q4.y
                 + __uint_as_float(w0.z & 0xffff0000u)*q4.z
                 + __uint_as_float(w0.w & 0xffff0000u)*q4.w;
        float d1 = __uint_as_float(w1.x & 0xffff0000u)*q4.x
                 + __uint_as_float(w1.y & 0xffff0000u)*q4.y
                 + __uint_as_float(w1.z & 0xffff0000u)*q4.z
                 + __uint_as_float(w1.w & 0xffff0000u)*q4.w;
        d0 += __shfl_xor(d0, 1); d1 += __shfl_xor(d1, 1);
        d0 += __shfl_xor(d0, 2); d1 += __shfl_xor(d1, 2);
        float mn0 = fmaxf(m0, d0), mn1 = fmaxf(m1, d1);
        float sc0 = __expf(m0 - mn0), sc1 = __expf(m1 - mn1);
        float wt0 = __expf(d0 - mn0), wt1 = __expf(d1 - mn1);
        l0 = l0*sc0 + wt0;               l1 = l1*sc1 + wt1;
        a0.x = a0.x*sc0 + wt0*__uint_as_float(w0.x << 16);
        a1.x = a1.x*sc1 + wt1*__uint_as_float(w1.x << 16);
        a0.y = a0.y*sc0 + wt0*__uint_as_float(w0.y << 16);
        a1.y = a1.y*sc1 + wt1*__uint_as_float(w1.y << 16);
        a0.z = a0.z*sc0 + wt0*__uint_as_float(w0.z << 16);
        a1.z = a1.z*sc1 + wt1*__uint_as_float(w1.z << 16);
        a0.w = a0.w*sc0 + wt0*__uint_as_float(w0.w << 16);
        a1.w = a1.w*sc1 + wt1*__uint_as_float(w1.w << 16);
        m0 = mn0; m1 = mn1;
    }
    if (pos < e) {       // last single edge -> state0
        uint4 w0 = w0n;
        float d = __uint_as_float(w0.x & 0xffff0000u)*q4.x
                + __uint_as_float(w0.y & 0xffff0000u)*q4.y
                + __uint_as_float(w0.z & 0xffff0000u)*q4.z
                + __uint_as_float(w0.w & 0xffff0000u)*q4.w;
        d += __shfl_xor(d, 1);
        d += __shfl_xor(d, 2);
        float mn = fmaxf(m0, d);
        float sc = __expf(m0 - mn);
        float wt = __expf(d - mn);
        l0 = l0*sc + wt;
        a0.x = a0.x*sc + wt*__uint_as_float(w0.x << 16);
        a0.y = a0.y*sc + wt*__uint_as_float(w0.y << 16);
        a0.z = a0.z*sc + wt*__uint_as_float(w0.z << 16);
        a0.w = a0.w*sc + wt*__uint_as_float(w0.w << 16);
        m0 = mn;
    }
    float mn = fmaxf(m0, m1);
    float sc0 = (m0 == -INFINITY) ? 0.f : __expf(m0 - mn);
    float sc1 = (m1 == -INFINITY) ? 0.f : __expf(m1 - mn);
    float lsum = l0*sc0 + l1*sc1;
    float4 acc;
    acc.x = a0.x*sc0 + a1.x*sc1;
    acc.y = a0.y*sc0 + a1.y*sc1;
    acc.z = a0.z*sc0 + a1.z*sc1;
    acc.w = a0.w*sc0 + a1.w*sc1;

    float inv = 1.f/(lsum + 1e-16f);
    float x0 = acc.x*inv, x1 = acc.y*inv, x2 = acc.z*inv, x3 = acc.w*inv;
    float4 o;
    o.x = 0.5f*x0*(1.f + erff(x0*0.70710678118654752f));
    o.y = 0.5f*x1*(1.f + erff(x1*0.70710678118654752f));
    o.z = 0.5f*x2*(1.f + erff(x2*0.70710678118654752f));
    o.w = 0.5f*x3*(1.f + erff(x3*0.70710678118654752f));
    *(float4*)&qa[(size_t)n*128 + lane*4] = o;
}

// head: one wave per node, shuffle reduce
__global__ __launch_bounds__(64) void k_head(
    const float* __restrict__ h, const float* __restrict__ hw,
    const float* __restrict__ hb, float* __restrict__ out, int n_nodes)
{
    int n = blockIdx.x;
    if (n >= n_nodes) return;
    int t = threadIdx.x;
    float h0 = h[(size_t)n*128 + t], h1 = h[(size_t)n*128 + 64 + t];
    float c0 = h0*hw[t*2]     + h1*hw[(t+64)*2];
    float c1 = h0*hw[t*2 + 1] + h1*hw[(t+64)*2 + 1];
    for (int off = 32; off > 0; off >>= 1) {
        c0 += __shfl_down(c0, off);
        c1 += __shfl_down(c1, off);
    }
    if (t == 0) {
        out[n*2]     = c0 + hb[0];
        out[n*2 + 1] = c1 + hb[1];
    }
}

extern "C" void kernel_launch(void* const* d_in, const int* in_sizes, int n_in,
                              void* d_out, int out_size, void* d_ws, size_t ws_size,
                              hipStream_t stream)
{
    const float* x      = (const float*)d_in[0];
    const int*   ef     = (const int*)d_in[1];
    const int*   er     = (const int*)d_in[2];
    const float* in_w   = (const float*)d_in[3];
    const float* in_b   = (const float*)d_in[4];
    const float* kqv_w  = (const float*)d_in[5];
    const float* kqv_b  = (const float*)d_in[6];
    const float* krel_w = (const float*)d_in[7];
    const float* vrel_w = (const float*)d_in[8];
    const float* p_rel  = (const float*)d_in[9];
    const float* out_w  = (const float*)d_in[10];
    const float* out_b  = (const float*)d_in[11];
    const float* skip   = (const float*)d_in[12];
    const float* head_w = (const float*)d_in[13];
    const float* head_b = (const float*)d_in[14];
    float* out = (float*)d_out;

    int n_nodes = in_sizes[0] / 128;
    int Ef = in_sizes[1] / 2, Er = in_sizes[2] / 2;
    int Etot = Ef + Er;
    int nch = (n_nodes + 255)/256;

    // workspace
    float* p = (float*)d_ws;
    float* h    = p; p += (size_t)n_nodes*128;
    float* qa   = p; p += (size_t)n_nodes*128;
    unsigned* kv = (unsigned*)p; p += (size_t)2*n_nodes*128;   // packed bf16 (k<<16)|v
    unsigned short* WcT = (unsigned short*)p; p += (size_t)(2*640*128)/2;
    float* biasc = p; p += 2*640;
    unsigned short* WoT = (unsigned short*)p; p += (size_t)(2*128*128)/2;
    float* biaso = p; p += 2*128;
    int* deg       = (int*)p;      p += n_nodes;
    int* csum      = (int*)p;      p += 1024;
    int* row_start = (int*)p;      p += n_nodes + 1;
    int* cursor    = (int*)p;      p += n_nodes + 1;
    unsigned* srcs = (unsigned*)p; p += Etot;

    int ntile = (n_nodes + 63)/64;
    int Rg = (ntile + 7)/8;

    // ---- CSR build + weight compose ----
    k_zero_i<<<(n_nodes + 255)/256, 256, 0, stream>>>(deg, n_nodes);
    k_count<<<1024, 256, 0, stream>>>(ef, er, deg, Ef, Er);
    k_chunk_sums<<<nch, 256, 0, stream>>>(deg, csum, n_nodes);
    k_scan_chunks<<<1, 1024, 0, stream>>>(csum, nch);
    k_rowstart<<<(n_nodes + 256)/256, 256, 0, stream>>>(deg, csum, row_start, cursor, n_nodes);
    k_fill<<<1024, 256, 0, stream>>>(ef, er, cursor, srcs, Ef, Er);
    k_compose<<<(2*129*640 + 255)/256, 256, 0, stream>>>(kqv_w, kqv_b, krel_w, vrel_w,
                                                         p_rel, WcT, biasc);
    k_compose_out<<<(2*129*128 + 255)/256, 256, 0, stream>>>(out_w, out_b, WoT, biaso);

    // ---- network ----
    k_gemm<<<ntile*2, 256, 0, stream>>>(x, in_w, 128, in_b, h, n_nodes, 2);
    for (int l = 0; l < 2; ++l) {
        k_mfma<<<Rg*8*10, 256, 0, stream>>>(h, WcT + (size_t)l*640*128,
                                            biasc + l*640, qa, kv, skip, l,
                                            n_nodes, ntile, 10, 1);
        k_attn<<<(n_nodes + 7)/8, 256, 0, stream>>>(srcs, row_start,
                                                    (const uint4*)kv, qa, n_nodes);
        k_mfma<<<Rg*8*2, 256, 0, stream>>>(qa, WoT + (size_t)l*128*128,
                                           biaso + l*128, h, kv, skip, l,
                                           n_nodes, ntile, 2, 2);
    }
    k_head<<<n_nodes, 64, 0, stream>>>(h, head_w, head_b, out, n_nodes);
}

// Round 13
// 479.719 us; speedup vs baseline: 1.6358x; 1.0355x over previous
//
#include <hip/hip_runtime.h>
#include <math.h>

typedef short short8 __attribute__((ext_vector_type(8)));
typedef float f32x4 __attribute__((ext_vector_type(4)));

// ---------------- helpers ----------------
__device__ __forceinline__ unsigned short f2bf(float f){   // RTN bf16
    unsigned u = __float_as_uint(f);
    unsigned r = u + 0x7fffu + ((u >> 16) & 1u);
    return (unsigned short)(r >> 16);
}

// ---------------- CSR build ----------------
__global__ void k_zero_i(int* __restrict__ p, int n)
{
    for (int i = blockIdx.x*blockDim.x + threadIdx.x; i < n; i += gridDim.x*blockDim.x)
        p[i] = 0;
}

__global__ void k_count(const int* __restrict__ ef, const int* __restrict__ er,
                        int* __restrict__ deg, int Ef, int Er)
{
    int Etot = Ef + Er;
    for (int e = blockIdx.x*blockDim.x + threadIdx.x; e < Etot; e += gridDim.x*blockDim.x) {
        int dst = (e < Ef) ? ef[Ef + e] : er[Er + (e - Ef)];
        atomicAdd(&deg[dst], 1);
    }
}

__global__ void k_chunk_sums(const int* __restrict__ deg, int* __restrict__ csum, int n)
{
    __shared__ int s[256];
    int t = threadIdx.x, i = blockIdx.x*256 + t;
    s[t] = (i < n) ? deg[i] : 0;
    __syncthreads();
    for (int off = 128; off > 0; off >>= 1) {
        if (t < off) s[t] += s[t + off];
        __syncthreads();
    }
    if (t == 0) csum[blockIdx.x] = s[0];
}

__global__ void k_scan_chunks(int* __restrict__ csum, int nch)
{
    __shared__ int s[1024];
    int t = threadIdx.x;
    int v = (t < nch) ? csum[t] : 0;
    s[t] = v; __syncthreads();
    for (int off = 1; off < 1024; off <<= 1) {
        int u = (t >= off) ? s[t - off] : 0;
        __syncthreads();
        s[t] += u;
        __syncthreads();
    }
    if (t < nch) csum[t] = s[t] - v;
}

__global__ void k_rowstart(const int* __restrict__ deg, const int* __restrict__ csum,
                           int* __restrict__ row_start, int* __restrict__ cursor, int n)
{
    __shared__ int s[256];
    int t = threadIdx.x, i = blockIdx.x*256 + t;
    int d = (i < n) ? deg[i] : 0;
    s[t] = d; __syncthreads();
    for (int off = 1; off < 256; off <<= 1) {
        int u = (t >= off) ? s[t - off] : 0;
        __syncthreads();
        s[t] += u;
        __syncthreads();
    }
    if (i <= n) {
        int rs = csum[blockIdx.x] + s[t] - d;   // exclusive
        row_start[i] = rs;
        cursor[i] = rs;
    }
}

// srcs[pos] = pre-baked uint4 row offset: (tt*n_nodes + src)*32
__global__ void k_fill(const int* __restrict__ ef, const int* __restrict__ er,
                       int* __restrict__ cursor, unsigned* __restrict__ srcs,
                       int Ef, int Er, int n_nodes)
{
    int Etot = Ef + Er;
    if (blockIdx.x == 0 && threadIdx.x == 0) {   // sentinel pad for branch-free prefetch
        srcs[Etot] = 0; srcs[Etot + 1] = 0;
    }
    for (int e = blockIdx.x*blockDim.x + threadIdx.x; e < Etot; e += gridDim.x*blockDim.x) {
        int src, dst, tt;
        if (e < Ef) { src = ef[e]; dst = ef[Ef + e]; tt = 0; }
        else { int e2 = e - Ef; src = er[e2]; dst = er[Er + e2]; tt = 1; }
        int pos = atomicAdd(&cursor[dst], 1);
        srcs[pos] = (unsigned)(tt*n_nodes + src)*32u;
    }
}

// ---------------- composed kqv weights (transposed, bf16) ----------------
// k columns scaled by p*0.25*(1/ln2): alpha lands in log2 domain -> bare v_exp_f32.
__global__ void k_compose(const float* __restrict__ kqv_w, const float* __restrict__ kqv_b,
                          const float* __restrict__ krel_w, const float* __restrict__ vrel_w,
                          const float* __restrict__ p_rel, unsigned short* __restrict__ WcT,
                          float* __restrict__ biasc)
{
    int idx = blockIdx.x*blockDim.x + threadIdx.x;
    int tot = 2*129*640;
    if (idx >= tot) return;
    int l = idx / (129*640);
    int rem = idx % (129*640);
    int r = rem / 640, c = rem % 640;
    float val;
    if (c < 128) {
        val = (r < 128) ? kqv_w[((size_t)l*128 + r)*384 + 128 + c]
                        : kqv_b[l*384 + 128 + c];
    } else {
        int c2 = c - 128;
        int tt = c2 >> 8;
        int cc = c2 & 255;
        int f = cc >> 1;
        int part = cc & 1;             // 0 = k, 1 = v
        int hh = f >> 4, fd = f & 15;
        const float* rw = (part == 0 ? krel_w : vrel_w)
                          + (((size_t)(l*2 + tt)*8 + hh)*16)*16 + fd;
        int base_col = (part == 0 ? 0 : 256) + hh*16;
        float s = 0.f;
        #pragma unroll
        for (int d = 0; d < 16; ++d) {
            float a = (r < 128) ? kqv_w[((size_t)l*128 + r)*384 + base_col + d]
                                : kqv_b[l*384 + base_col + d];
            s += a * rw[d*16];
        }
        if (part == 0) s *= p_rel[(l*2 + tt)*8 + hh] * 0.25f * 1.4426950408889634f;
        val = s;
    }
    if (r < 128) WcT[((size_t)l*640 + c)*128 + r] = f2bf(val);
    else         biasc[l*640 + c] = val;
}

// out_w -> transposed bf16 WoT[l][c][k], biaso = out_b
__global__ void k_compose_out(const float* __restrict__ out_w, const float* __restrict__ out_b,
                              unsigned short* __restrict__ WoT, float* __restrict__ biaso)
{
    int idx = blockIdx.x*blockDim.x + threadIdx.x;
    int tot = 2*129*128;
    if (idx >= tot) return;
    int l = idx / (129*128);
    int rem = idx % (129*128);
    int r = rem / 128, c = rem % 128;
    if (r < 128) WoT[((size_t)l*128 + c)*128 + r] = f2bf(out_w[((size_t)l*128 + r)*128 + c]);
    else         biaso[l*128 + c] = out_b[l*128 + c];
}

// ---------------- unified MFMA GEMM (bf16 in, f32 accum) ----------------
__global__ __launch_bounds__(256) void k_mfma(
    const float* __restrict__ A, const unsigned short* __restrict__ WT,
    const float* __restrict__ biasc, float* __restrict__ out0,
    unsigned* __restrict__ kv, const float* __restrict__ skip, int l,
    int n_nodes, int R, int C, int mode)
{
    __shared__ uint4 As[64*16];
    __shared__ uint4 Ws[64*16];
    int b = blockIdx.x;
    int xcd = b & 7, jj = b >> 3;
    int r_t = (jj / C)*8 + xcd;
    int c_t = jj % C;
    if (r_t >= R) return;
    int n0 = r_t*64, c0 = c_t*64;
    int t = threadIdx.x;

    #pragma unroll
    for (int it = 0; it < 4; ++it) {
        int gi = t + it*256;
        int m = gi >> 4, g = gi & 15;
        int n = n0 + m;
        float4 a0 = make_float4(0.f,0.f,0.f,0.f), a1 = a0;
        if (n < n_nodes) {
            a0 = *(const float4*)&A[(size_t)n*128 + g*8];
            a1 = *(const float4*)&A[(size_t)n*128 + g*8 + 4];
        }
        uint4 wd;
        wd.x = (unsigned)f2bf(a0.x) | ((unsigned)f2bf(a0.y) << 16);
        wd.y = (unsigned)f2bf(a0.z) | ((unsigned)f2bf(a0.w) << 16);
        wd.z = (unsigned)f2bf(a1.x) | ((unsigned)f2bf(a1.y) << 16);
        wd.w = (unsigned)f2bf(a1.z) | ((unsigned)f2bf(a1.w) << 16);
        As[m*16 + (g ^ (m & 15))] = wd;
    }
    #pragma unroll
    for (int it = 0; it < 4; ++it) {
        int gi = t + it*256;
        int cw = gi >> 4, g = gi & 15;
        uint4 wv = *(const uint4*)&WT[((size_t)(c0 + cw))*128 + g*8];
        Ws[cw*16 + (g ^ (cw & 15))] = wv;
    }
    __syncthreads();

    int lane = t & 63, w = t >> 6;
    int lm = lane & 15, quad = lane >> 4;
    f32x4 acc[4];
    #pragma unroll
    for (int i = 0; i < 4; ++i) { acc[i][0]=0.f; acc[i][1]=0.f; acc[i][2]=0.f; acc[i][3]=0.f; }

    #pragma unroll
    for (int chunk = 0; chunk < 4; ++chunk) {
        int gq = chunk*4 + quad;
        short8 bfrag = *(const short8*)&Ws[(w*16 + lm)*16 + (gq ^ lm)];
        #pragma unroll
        for (int i = 0; i < 4; ++i) {
            short8 afrag = *(const short8*)&As[(i*16 + lm)*16 + (gq ^ lm)];
            acc[i] = __builtin_amdgcn_mfma_f32_16x16x32_bf16(afrag, bfrag, acc[i], 0, 0, 0);
        }
    }

    int c = c0 + w*16 + lm;
    float bc = biasc[c];
    if (mode == 2) {
        float g = 1.f/(1.f + expf(-skip[l]));
        #pragma unroll
        for (int i = 0; i < 4; ++i) {
            #pragma unroll
            for (int rr = 0; rr < 4; ++rr) {
                int m = n0 + i*16 + quad*4 + rr;
                if (m < n_nodes) {
                    size_t o = (size_t)m*128 + c;
                    float hv = out0[o];
                    out0[o] = fmaxf(g*(acc[i][rr] + bc) + (1.f - g)*hv, 0.f);
                }
            }
        }
    } else if (c0 < 128) {
        #pragma unroll
        for (int i = 0; i < 4; ++i) {
            #pragma unroll
            for (int rr = 0; rr < 4; ++rr) {
                int m = n0 + i*16 + quad*4 + rr;
                if (m < n_nodes) out0[(size_t)m*128 + c] = acc[i][rr] + bc;
            }
        }
    } else {
        int c2 = c - 128;
        int tt = c2 >> 8;
        int f = (c2 & 255) >> 1;
        unsigned* dst = kv + (size_t)tt*n_nodes*128;
        bool isk = (lane & 1) == 0;
        #pragma unroll
        for (int i = 0; i < 4; ++i) {
            #pragma unroll
            for (int rr = 0; rr < 4; ++rr) {
                float val = acc[i][rr] + bc;
                float other = __shfl_xor(val, 1);
                int m = n0 + i*16 + quad*4 + rr;
                if (isk && m < n_nodes) {
                    unsigned wd = ((unsigned)f2bf(val) << 16) | (unsigned)f2bf(other);
                    dst[(size_t)m*128 + f] = wd;
                }
            }
        }
    }
}

// ---------------- f32 tiled GEMM (in_proj only) ----------------
__global__ __launch_bounds__(256) void k_gemm(
    const float* __restrict__ A, const float* __restrict__ W, int ldw,
    const float* __restrict__ bias, float* __restrict__ out0,
    int n_nodes, int ncol_tiles)
{
    __shared__ float As_t[32][64];
    __shared__ float Ws[32][64];
    int tile_n = blockIdx.x / ncol_tiles;
    int tile_c = blockIdx.x % ncol_tiles;
    int n0 = tile_n*64, c0 = tile_c*64;
    int t = threadIdx.x, tx = t & 15, ty = t >> 4;

    float4 b4 = *(const float4*)&bias[c0 + tx*4];
    float acc[4][4];
    #pragma unroll
    for (int r = 0; r < 4; ++r) {
        acc[r][0] = b4.x; acc[r][1] = b4.y; acc[r][2] = b4.z; acc[r][3] = b4.w;
    }

    for (int kk = 0; kk < 128; kk += 32) {
        __syncthreads();
        #pragma unroll
        for (int it = 0; it < 2; ++it) {
            int idx = t + it*256;
            int m = idx >> 3, c4 = idx & 7;
            int n = n0 + m;
            float4 a = make_float4(0.f, 0.f, 0.f, 0.f);
            if (n < n_nodes) a = *(const float4*)&A[(size_t)n*128 + kk + c4*4];
            int col = m ^ (c4 << 3);
            As_t[c4*4 + 0][col] = a.x;
            As_t[c4*4 + 1][col] = a.y;
            As_t[c4*4 + 2][col] = a.z;
            As_t[c4*4 + 3][col] = a.w;
        }
        #pragma unroll
        for (int it = 0; it < 2; ++it) {
            int idx = t + it*256;
            int r = idx >> 4, c4 = idx & 15;
            *(float4*)&Ws[r][c4*4] = *(const float4*)&W[(size_t)(kk + r)*ldw + c0 + c4*4];
        }
        __syncthreads();
        #pragma unroll 8
        for (int k = 0; k < 32; ++k) {
            float4 a = *(const float4*)&As_t[k][(ty*4) ^ ((k >> 2) << 3)];
            float4 w = *(const float4*)&Ws[k][tx*4];
            acc[0][0] += a.x*w.x; acc[0][1] += a.x*w.y; acc[0][2] += a.x*w.z; acc[0][3] += a.x*w.w;
            acc[1][0] += a.y*w.x; acc[1][1] += a.y*w.y; acc[1][2] += a.y*w.z; acc[1][3] += a.y*w.w;
            acc[2][0] += a.z*w.x; acc[2][1] += a.z*w.y; acc[2][2] += a.z*w.z; acc[2][3] += a.z*w.w;
            acc[3][0] += a.w*w.x; acc[3][1] += a.w*w.y; acc[3][2] += a.w*w.z; acc[3][3] += a.w*w.w;
        }
    }

    #pragma unroll
    for (int r = 0; r < 4; ++r) {
        int n = n0 + ty*4 + r;
        if (n >= n_nodes) break;
        float4 o = make_float4(acc[r][0], acc[r][1], acc[r][2], acc[r][3]);
        *(float4*)&out0[(size_t)n*128 + c0 + tx*4] = o;
    }
}

// ---------------- fused gather attention ----------------
// srcs pre-baked as uint4 row offsets; sentinel-padded -> branch-free prefetch;
// k pre-scaled by 1/ln2 -> exp2f (bare v_exp_f32). 2-state online softmax.
__global__ __launch_bounds__(256) void k_attn(
    const unsigned* __restrict__ srcs, const int* __restrict__ row_start,
    const uint4* __restrict__ kv, float* __restrict__ qa, int n_nodes)
{
    int lane = threadIdx.x & 31;
    int n = blockIdx.x*8 + (threadIdx.x >> 5);
    if (n >= n_nodes) return;
    float4 q4 = *(const float4*)&qa[(size_t)n*128 + lane*4];
    int s = row_start[n], e = row_start[n + 1];

    float m0 = -INFINITY, l0 = 0.f; float4 a0 = make_float4(0.f,0.f,0.f,0.f);
    float m1 = -INFINITY, l1 = 0.f; float4 a1 = make_float4(0.f,0.f,0.f,0.f);

    uint4 w0n = kv[srcs[s] + lane];
    uint4 w1n = kv[srcs[s + 1] + lane];
    int pos = s;
    for (; pos + 1 < e; pos += 2) {
        uint4 w0 = w0n, w1 = w1n;
        unsigned sv0 = srcs[pos + 2], sv1 = srcs[pos + 3];
        w0n = kv[sv0 + lane];
        w1n = kv[sv1 + lane];
        float d0 = __uint_as_float(w0.x & 0xffff0000u)*q4.x
                 + __uint_as_float(w0.y & 0xffff0000u)*q4.y
                 + __uint_as_float(w0.z & 0xffff0000u)*q4.z
                 + __uint_as_float(w0.w & 0xffff0000u)*q4.w;
        float d1 = __uint_as_float(w1.x & 0xffff0000u)*q4.x
                 + __uint_as_float(w1.y & 0xffff0000u)*q4.y
                 + __uint_as_float(w1.z & 0xffff0000u)*q4.z
                 + __uint_as_float(w1.w & 0xffff0000u)*q4.w;
        d0 += __shfl_xor(d0, 1); d1 += __shfl_xor(d1, 1);
        d0 += __shfl_xor(d0, 2); d1 += __shfl_xor(d1, 2);
        float mn0 = fmaxf(m0, d0), mn1 = fmaxf(m1, d1);
        float sc0 = exp2f(m0 - mn0), sc1 = exp2f(m1 - mn1);
        float wt0 = exp2f(d0 - mn0), wt1 = exp2f(d1 - mn1);
        l0 = l0*sc0 + wt0;               l1 = l1*sc1 + wt1;
        a0.x = a0.x*sc0 + wt0*__uint_as_float(w0.x << 16);
        a1.x = a1.x*sc1 + wt1*__uint_as_float(w1.x << 16);
        a0.y = a0.y*sc0 + wt0*__uint_as_float(w0.y << 16);
        a1.y = a1.y*sc1 + wt1*__uint_as_float(w1.y << 16);
        a0.z = a0.z*sc0 + wt0*__uint_as_float(w0.z << 16);
        a1.z = a1.z*sc1 + wt1*__uint_as_float(w1.z << 16);
        a0.w = a0.w*sc0 + wt0*__uint_as_float(w0.w << 16);
        a1.w = a1.w*sc1 + wt1*__uint_as_float(w1.w << 16);
        m0 = mn0; m1 = mn1;
    }
    if (pos < e) {       // last single edge -> state0
        uint4 w0 = w0n;
        float d = __uint_as_float(w0.x & 0xffff0000u)*q4.x
                + __uint_as_float(w0.y & 0xffff0000u)*q4.y
                + __uint_as_float(w0.z & 0xffff0000u)*q4.z
                + __uint_as_float(w0.w & 0xffff0000u)*q4.w;
        d += __shfl_xor(d, 1);
        d += __shfl_xor(d, 2);
        float mn = fmaxf(m0, d);
        float sc = exp2f(m0 - mn);
        float wt = exp2f(d - mn);
        l0 = l0*sc + wt;
        a0.x = a0.x*sc + wt*__uint_as_float(w0.x << 16);
        a0.y = a0.y*sc + wt*__uint_as_float(w0.y << 16);
        a0.z = a0.z*sc + wt*__uint_as_float(w0.z << 16);
        a0.w = a0.w*sc + wt*__uint_as_float(w0.w << 16);
        m0 = mn;
    }
    float mn = fmaxf(m0, m1);
    float sc0 = (m0 == -INFINITY) ? 0.f : exp2f(m0 - mn);
    float sc1 = (m1 == -INFINITY) ? 0.f : exp2f(m1 - mn);
    float lsum = l0*sc0 + l1*sc1;
    float4 acc;
    acc.x = a0.x*sc0 + a1.x*sc1;
    acc.y = a0.y*sc0 + a1.y*sc1;
    acc.z = a0.z*sc0 + a1.z*sc1;
    acc.w = a0.w*sc0 + a1.w*sc1;

    float inv = 1.f/(lsum + 1e-16f);
    float x0 = acc.x*inv, x1 = acc.y*inv, x2 = acc.z*inv, x3 = acc.w*inv;
    float4 o;
    o.x = 0.5f*x0*(1.f + erff(x0*0.70710678118654752f));
    o.y = 0.5f*x1*(1.f + erff(x1*0.70710678118654752f));
    o.z = 0.5f*x2*(1.f + erff(x2*0.70710678118654752f));
    o.w = 0.5f*x3*(1.f + erff(x3*0.70710678118654752f));
    *(float4*)&qa[(size_t)n*128 + lane*4] = o;
}

// head: 4 nodes per 256-thr block, shuffle reduce within 64-lane groups
__global__ __launch_bounds__(256) void k_head(
    const float* __restrict__ h, const float* __restrict__ hw,
    const float* __restrict__ hb, float* __restrict__ out, int n_nodes)
{
    int n = blockIdx.x*4 + (threadIdx.x >> 6);
    if (n >= n_nodes) return;
    int t = threadIdx.x & 63;
    float h0 = h[(size_t)n*128 + t], h1 = h[(size_t)n*128 + 64 + t];
    float c0 = h0*hw[t*2]     + h1*hw[(t+64)*2];
    float c1 = h0*hw[t*2 + 1] + h1*hw[(t+64)*2 + 1];
    for (int off = 32; off > 0; off >>= 1) {
        c0 += __shfl_down(c0, off);
        c1 += __shfl_down(c1, off);
    }
    if (t == 0) {
        out[n*2]     = c0 + hb[0];
        out[n*2 + 1] = c1 + hb[1];
    }
}

extern "C" void kernel_launch(void* const* d_in, const int* in_sizes, int n_in,
                              void* d_out, int out_size, void* d_ws, size_t ws_size,
                              hipStream_t stream)
{
    const float* x      = (const float*)d_in[0];
    const int*   ef     = (const int*)d_in[1];
    const int*   er     = (const int*)d_in[2];
    const float* in_w   = (const float*)d_in[3];
    const float* in_b   = (const float*)d_in[4];
    const float* kqv_w  = (const float*)d_in[5];
    const float* kqv_b  = (const float*)d_in[6];
    const float* krel_w = (const float*)d_in[7];
    const float* vrel_w = (const float*)d_in[8];
    const float* p_rel  = (const float*)d_in[9];
    const float* out_w  = (const float*)d_in[10];
    const float* out_b  = (const float*)d_in[11];
    const float* skip   = (const float*)d_in[12];
    const float* head_w = (const float*)d_in[13];
    const float* head_b = (const float*)d_in[14];
    float* out = (float*)d_out;

    int n_nodes = in_sizes[0] / 128;
    int Ef = in_sizes[1] / 2, Er = in_sizes[2] / 2;
    int Etot = Ef + Er;
    int nch = (n_nodes + 255)/256;

    // workspace
    float* p = (float*)d_ws;
    float* h    = p; p += (size_t)n_nodes*128;
    float* qa   = p; p += (size_t)n_nodes*128;
    unsigned* kv = (unsigned*)p; p += (size_t)2*n_nodes*128;   // packed bf16 (k<<16)|v
    unsigned short* WcT = (unsigned short*)p; p += (size_t)(2*640*128)/2;
    float* biasc = p; p += 2*640;
    unsigned short* WoT = (unsigned short*)p; p += (size_t)(2*128*128)/2;
    float* biaso = p; p += 2*128;
    int* deg       = (int*)p;      p += n_nodes;
    int* csum      = (int*)p;      p += 1024;
    int* row_start = (int*)p;      p += n_nodes + 1;
    int* cursor    = (int*)p;      p += n_nodes + 1;
    unsigned* srcs = (unsigned*)p; p += Etot + 2;   // +2 sentinel pad

    int ntile = (n_nodes + 63)/64;
    int Rg = (ntile + 7)/8;

    // ---- CSR build + weight compose ----
    k_zero_i<<<(n_nodes + 255)/256, 256, 0, stream>>>(deg, n_nodes);
    k_count<<<1024, 256, 0, stream>>>(ef, er, deg, Ef, Er);
    k_chunk_sums<<<nch, 256, 0, stream>>>(deg, csum, n_nodes);
    k_scan_chunks<<<1, 1024, 0, stream>>>(csum, nch);
    k_rowstart<<<(n_nodes + 256)/256, 256, 0, stream>>>(deg, csum, row_start, cursor, n_nodes);
    k_fill<<<1024, 256, 0, stream>>>(ef, er, cursor, srcs, Ef, Er, n_nodes);
    k_compose<<<(2*129*640 + 255)/256, 256, 0, stream>>>(kqv_w, kqv_b, krel_w, vrel_w,
                                                         p_rel, WcT, biasc);
    k_compose_out<<<(2*129*128 + 255)/256, 256, 0, stream>>>(out_w, out_b, WoT, biaso);

    // ---- network ----
    k_gemm<<<ntile*2, 256, 0, stream>>>(x, in_w, 128, in_b, h, n_nodes, 2);
    for (int l = 0; l < 2; ++l) {
        k_mfma<<<Rg*8*10, 256, 0, stream>>>(h, WcT + (size_t)l*640*128,
                                            biasc + l*640, qa, kv, skip, l,
                                            n_nodes, ntile, 10, 1);
        k_attn<<<(n_nodes + 7)/8, 256, 0, stream>>>(srcs, row_start,
                                                    (const uint4*)kv, qa, n_nodes);
        k_mfma<<<Rg*8*2, 256, 0, stream>>>(qa, WoT + (size_t)l*128*128,
                                           biaso + l*128, h, kv, skip, l,
                                           n_nodes, ntile, 2, 2);
    }
    k_head<<<(n_nodes + 3)/4, 256, 0, stream>>>(h, head_w, head_b, out, n_nodes);
}